// Round 7
// baseline (193.194 us; speedup 1.0000x reference)
//
#include <hip/hip_runtime.h>
#include <hip/hip_cooperative_groups.h>

namespace cg = cooperative_groups;

typedef float f4 __attribute__((ext_vector_type(4)));   // native vec type for NT builtins

#define NBLK 1024
#define NTHR 256
#define RPB  (NTHR * 4)        // rows per block = 1024

// One cooperative kernel: count -> grid.sync -> prefix -> rank(LDS) -> scatter copy.
// 1024 blocks x 256 threads = 4 blocks/CU (co-resident; LDS 5KB/block, VGPR capped 128).
__global__ __launch_bounds__(NTHR, 4)
void dps_all(const f4* __restrict__ data4,
             const int* __restrict__ parts,
             const int* __restrict__ index0,
             const int* __restrict__ index1,
             int* __restrict__ bs,          // NBLK ints in ws
             int n,
             f4* __restrict__ out4) {
    __shared__ int lds[NTHR];
    __shared__ int dstL[RPB];
    const int t    = threadIdx.x;
    const int b    = blockIdx.x;
    const int base = b * RPB;              // first row of this block

    // ---- Phase A: 4 parts/thread (registers), block inclusive scan ----
    int v0 = 0, v1 = 0, v2 = 0, v3 = 0;
    {
        int i0 = base + t * 4;
        if (i0 + 3 < n) {
            int4 p = reinterpret_cast<const int4*>(parts)[(base >> 2) + t];
            v0 = p.x; v1 = p.y; v2 = p.z; v3 = p.w;
        } else {
            if (i0 + 0 < n) v0 = parts[i0 + 0];
            if (i0 + 1 < n) v1 = parts[i0 + 1];
            if (i0 + 2 < n) v2 = parts[i0 + 2];
            if (i0 + 3 < n) v3 = parts[i0 + 3];
        }
    }
    int s = v0 + v1 + v2 + v3;
    lds[t] = s;
    __syncthreads();
    for (int off = 1; off < NTHR; off <<= 1) {
        int add = (t >= off) ? lds[t - off] : 0;
        __syncthreads();
        lds[t] += add;
        __syncthreads();
    }
    const int texcl = lds[t] - s;          // ones in this block before thread t's chunk
    if (t == 0) bs[b] = lds[NTHR - 1];     // block total
    __threadfence();                       // device-scope release before grid sync
    cg::this_grid().sync();

    // ---- Phase B: block_excl = sum of bs[0..b) (masked reduce, all threads) ----
    int partial = 0;
    {
        int4 q = reinterpret_cast<const int4*>(bs)[t];   // covers bs[4t..4t+4)
        int e = t * 4;
        if (e + 0 < b) partial += q.x;
        if (e + 1 < b) partial += q.y;
        if (e + 2 < b) partial += q.z;
        if (e + 3 < b) partial += q.w;
    }
    __syncthreads();
    lds[t] = partial;
    __syncthreads();
    for (int off = NTHR / 2; off > 0; off >>= 1) {
        if (t < off) lds[t] += lds[t + off];
        __syncthreads();
    }
    const int block_excl = lds[0];

    // ---- Phase C: ranks -> destination rows in LDS (no global dst array) ----
    {
        int ones = block_excl + texcl;     // global #ones before element i0
        int i0 = base + t * 4;
        int d0 = 0, d1 = 0, d2 = 0, d3 = 0;
        if (i0 + 0 < n) { d0 = v0 ? index1[ones] : index0[i0 + 0 - ones]; ones += v0; }
        if (i0 + 1 < n) { d1 = v1 ? index1[ones] : index0[i0 + 1 - ones]; ones += v1; }
        if (i0 + 2 < n) { d2 = v2 ? index1[ones] : index0[i0 + 2 - ones]; ones += v2; }
        if (i0 + 3 < n) { d3 = v3 ? index1[ones] : index0[i0 + 3 - ones]; ones += v3; }
        dstL[t * 4 + 0] = d0; dstL[t * 4 + 1] = d1;
        dstL[t * 4 + 2] = d2; dstL[t * 4 + 3] = d3;
    }
    __syncthreads();

    // ---- Phase D: copy RPB rows — NT coalesced reads, 4-deep MLP, scattered stores ----
    const f4* src = data4 + ((long)base << 4);
    if (base + RPB <= n) {
        #pragma unroll
        for (int it = 0; it < 16; ++it) {
            f4 w[4]; long o[4];
            #pragma unroll
            for (int k = 0; k < 4; ++k) {
                int id = it * 1024 + k * 256 + t;          // contiguous slab per k
                w[k] = __builtin_nontemporal_load(src + id);
                int row = id >> 4, q = id & 15;
                o[k] = ((long)dstL[row] << 4) + q;
            }
            #pragma unroll
            for (int k = 0; k < 4; ++k) out4[o[k]] = w[k]; // normal (cached) store
        }
    } else {
        int rem = (n - base) * 16;                          // may be <= 0
        for (int id = t; id < rem; id += NTHR) {
            int row = id >> 4, q = id & 15;
            f4 w = src[id];
            out4[((long)dstL[row] << 4) + q] = w;
        }
    }
}

extern "C" void kernel_launch(void* const* d_in, const int* in_sizes, int n_in,
                              void* d_out, int out_size, void* d_ws, size_t ws_size,
                              hipStream_t stream) {
    const f4*  data4  = (const f4*)d_in[0];
    const int* parts  = (const int*)d_in[1];
    const int* index0 = (const int*)d_in[2];
    const int* index1 = (const int*)d_in[3];
    f4*        out4   = (f4*)d_out;
    int n = in_sizes[1];
    int* bs = (int*)d_ws;                    // NBLK ints

    void* args[] = { (void*)&data4, (void*)&parts, (void*)&index0, (void*)&index1,
                     (void*)&bs, (void*)&n, (void*)&out4 };
    hipLaunchCooperativeKernel((void*)dps_all, dim3(NBLK), dim3(NTHR), args, 0, stream);
}

// Round 8
// 144.535 us; speedup vs baseline: 1.3367x; 1.3367x over previous
//
#include <hip/hip_runtime.h>

#define SCAN_BLOCK 256
#define EPT 16                      // partition elements per thread
#define CHUNK (SCAN_BLOCK * EPT)    // 4096 elements per block -> 256 chunks for n=1<<20

typedef float f4 __attribute__((ext_vector_type(4)));   // native vec type for NT builtins

// ---------- Pass 1: count ones per chunk ----------
__global__ __launch_bounds__(SCAN_BLOCK)
void dps_count(const int* __restrict__ parts, int n, int* __restrict__ block_sums) {
    const int t  = threadIdx.x;
    const int e0 = blockIdx.x * CHUNK + t * EPT;
    int s = 0;
    if (e0 + EPT <= n) {
        const int4* p4 = reinterpret_cast<const int4*>(parts + e0);
        #pragma unroll
        for (int k = 0; k < EPT / 4; ++k) {
            int4 v = p4[k];
            s += v.x + v.y + v.z + v.w;
        }
    } else {
        for (int j = 0; j < EPT; ++j) {
            int i = e0 + j;
            if (i < n) s += parts[i];
        }
    }
    #pragma unroll
    for (int off = 32; off >= 1; off >>= 1) s += __shfl_down(s, off, 64);
    __shared__ int lds[SCAN_BLOCK / 64];
    if ((t & 63) == 0) lds[t >> 6] = s;
    __syncthreads();
    if (t == 0) {
        int tot = 0;
        #pragma unroll
        for (int w = 0; w < SCAN_BLOCK / 64; ++w) tot += lds[w];
        block_sums[blockIdx.x] = tot;
    }
}

// ---------- Pass 2: rank (computes its own chunk prefix) -> dst[i] ----------
__global__ __launch_bounds__(SCAN_BLOCK)
void dps_rank(const int* __restrict__ parts,
              const int* __restrict__ index0,
              const int* __restrict__ index1,
              const int* __restrict__ block_sums,   // raw per-chunk totals (nchunks <= 256)
              int nchunks,
              int n, int* __restrict__ dst) {
    const int t  = threadIdx.x;
    const int b  = blockIdx.x;
    const int e0 = b * CHUNK + t * EPT;
    __shared__ int lds[SCAN_BLOCK];

    // -- block_excl = sum of block_sums[0..b) via masked tree reduce --
    int m = (t < b && t < nchunks) ? block_sums[t] : 0;
    lds[t] = m;
    __syncthreads();
    for (int off = SCAN_BLOCK / 2; off > 0; off >>= 1) {
        if (t < off) lds[t] += lds[t + off];
        __syncthreads();
    }
    const int block_excl = lds[0];
    __syncthreads();

    // -- load this thread's EPT partition values --
    int vals[EPT];
    int s = 0;
    if (e0 + EPT <= n) {
        const int4* p4 = reinterpret_cast<const int4*>(parts + e0);
        #pragma unroll
        for (int k = 0; k < EPT / 4; ++k) {
            int4 v = p4[k];
            vals[k * 4 + 0] = v.x; vals[k * 4 + 1] = v.y;
            vals[k * 4 + 2] = v.z; vals[k * 4 + 3] = v.w;
            s += v.x + v.y + v.z + v.w;
        }
    } else {
        for (int j = 0; j < EPT; ++j) {
            int i = e0 + j;
            vals[j] = (i < n) ? parts[i] : 0;
            s += vals[j];
        }
    }

    // -- in-block inclusive scan of per-thread sums --
    lds[t] = s;
    __syncthreads();
    for (int off = 1; off < SCAN_BLOCK; off <<= 1) {
        int add = (t >= off) ? lds[t - off] : 0;
        __syncthreads();
        lds[t] += add;
        __syncthreads();
    }
    int ones_before = block_excl + (lds[t] - s);

    int dv[EPT];
    #pragma unroll
    for (int j = 0; j < EPT; ++j) {
        int i = e0 + j;
        if (i < n) {
            dv[j] = vals[j] ? index1[ones_before] : index0[i - ones_before];
            ones_before += vals[j];
        }
    }
    if (e0 + EPT <= n) {
        int4* d4 = reinterpret_cast<int4*>(dst + e0);
        #pragma unroll
        for (int k = 0; k < EPT / 4; ++k)
            d4[k] = make_int4(dv[k*4+0], dv[k*4+1], dv[k*4+2], dv[k*4+3]);
    } else {
        for (int j = 0; j < EPT; ++j) {
            int i = e0 + j;
            if (i < n) dst[i] = dv[j];
        }
    }
}

// ---------- Pass 3: scatter copy — NT coalesced reads, 8-deep MLP, normal stores ----------
// Block of 512 threads covers one contiguous 4096-f4 slab (256 rows).
// Sub-slab k: ids [base + k*512, base + k*512 + 512) — fully coalesced reads.
__global__ __launch_bounds__(512)
void dps_scatter(const f4* __restrict__ data4,
                 const int* __restrict__ dst,
                 f4* __restrict__ out4,
                 long total4) {
    const long base = (long)blockIdx.x * 4096 + threadIdx.x;
    f4   v[8];
    long o[8];
    bool ok[8];
    #pragma unroll
    for (int k = 0; k < 8; ++k) {
        long id = base + (long)k * 512;
        ok[k] = (id < total4);
        if (ok[k]) {
            v[k] = __builtin_nontemporal_load(data4 + id);   // read-once: bypass caches
            int row = (int)(id >> 4);
            int q   = (int)(id & 15);
            o[k] = ((long)dst[row] << 4) + q;                // broadcast across the row's lanes
        }
    }
    #pragma unroll
    for (int k = 0; k < 8; ++k)
        if (ok[k]) out4[o[k]] = v[k];                        // normal (cached) store
}

extern "C" void kernel_launch(void* const* d_in, const int* in_sizes, int n_in,
                              void* d_out, int out_size, void* d_ws, size_t ws_size,
                              hipStream_t stream) {
    const float* data   = (const float*)d_in[0];
    const int*   parts  = (const int*)d_in[1];
    const int*   index0 = (const int*)d_in[2];
    const int*   index1 = (const int*)d_in[3];
    const int n = in_sizes[1];

    int* dst        = (int*)d_ws;              // n ints
    int* block_sums = dst + n;                 // nchunks ints

    const int nchunks = (n + CHUNK - 1) / CHUNK;   // 256 for n = 1<<20

    dps_count<<<nchunks, SCAN_BLOCK, 0, stream>>>(parts, n, block_sums);
    dps_rank <<<nchunks, SCAN_BLOCK, 0, stream>>>(parts, index0, index1, block_sums,
                                                  nchunks, n, dst);

    const long total4 = (long)n << 4;                      // n * (64/4)
    const int  blocks = (int)((total4 + 4095) / 4096);     // 4096 for n = 1<<20
    dps_scatter<<<blocks, 512, 0, stream>>>((const f4*)data, dst, (f4*)d_out, total4);
}

// Round 9
// 99.351 us; speedup vs baseline: 1.9446x; 1.4548x over previous
//
#include <hip/hip_runtime.h>

#define SCAN_BLOCK 256
#define EPT 16                      // partition elements per thread
#define CHUNK (SCAN_BLOCK * EPT)    // 4096 elements per block -> 256 chunks for n=1<<20

typedef float f4 __attribute__((ext_vector_type(4)));   // native vec type for NT builtins

// ---------- Pass 1: count ones per chunk ----------
__global__ __launch_bounds__(SCAN_BLOCK)
void dps_count(const int* __restrict__ parts, int n, int* __restrict__ block_sums) {
    const int t  = threadIdx.x;
    const int e0 = blockIdx.x * CHUNK + t * EPT;
    int s = 0;
    if (e0 + EPT <= n) {
        const int4* p4 = reinterpret_cast<const int4*>(parts + e0);
        #pragma unroll
        for (int k = 0; k < EPT / 4; ++k) {
            int4 v = p4[k];
            s += v.x + v.y + v.z + v.w;
        }
    } else {
        for (int j = 0; j < EPT; ++j) {
            int i = e0 + j;
            if (i < n) s += parts[i];
        }
    }
    #pragma unroll
    for (int off = 32; off >= 1; off >>= 1) s += __shfl_down(s, off, 64);
    __shared__ int lds[SCAN_BLOCK / 64];
    if ((t & 63) == 0) lds[t >> 6] = s;
    __syncthreads();
    if (t == 0) {
        int tot = 0;
        #pragma unroll
        for (int w = 0; w < SCAN_BLOCK / 64; ++w) tot += lds[w];
        block_sums[blockIdx.x] = tot;
    }
}

// ---------- Pass 2: rank (computes own chunk prefix from raw sums) -> dst[i] ----------
__global__ __launch_bounds__(SCAN_BLOCK)
void dps_rank(const int* __restrict__ parts,
              const int* __restrict__ index0,
              const int* __restrict__ index1,
              const int* __restrict__ block_sums,   // raw per-chunk totals (nchunks <= 256)
              int nchunks,
              int n, int* __restrict__ dst) {
    const int t  = threadIdx.x;
    const int b  = blockIdx.x;
    const int e0 = b * CHUNK + t * EPT;
    __shared__ int lds[SCAN_BLOCK];

    // -- block_excl = sum of block_sums[0..b) via masked tree reduce --
    int m = (t < b && t < nchunks) ? block_sums[t] : 0;
    lds[t] = m;
    __syncthreads();
    for (int off = SCAN_BLOCK / 2; off > 0; off >>= 1) {
        if (t < off) lds[t] += lds[t + off];
        __syncthreads();
    }
    const int block_excl = lds[0];
    __syncthreads();

    // -- load this thread's EPT partition values --
    int vals[EPT];
    int s = 0;
    if (e0 + EPT <= n) {
        const int4* p4 = reinterpret_cast<const int4*>(parts + e0);
        #pragma unroll
        for (int k = 0; k < EPT / 4; ++k) {
            int4 v = p4[k];
            vals[k * 4 + 0] = v.x; vals[k * 4 + 1] = v.y;
            vals[k * 4 + 2] = v.z; vals[k * 4 + 3] = v.w;
            s += v.x + v.y + v.z + v.w;
        }
    } else {
        for (int j = 0; j < EPT; ++j) {
            int i = e0 + j;
            vals[j] = (i < n) ? parts[i] : 0;
            s += vals[j];
        }
    }

    // -- in-block inclusive scan of per-thread sums --
    lds[t] = s;
    __syncthreads();
    for (int off = 1; off < SCAN_BLOCK; off <<= 1) {
        int add = (t >= off) ? lds[t - off] : 0;
        __syncthreads();
        lds[t] += add;
        __syncthreads();
    }
    int ones_before = block_excl + (lds[t] - s);

    int dv[EPT];
    #pragma unroll
    for (int j = 0; j < EPT; ++j) {
        int i = e0 + j;
        if (i < n) {
            dv[j] = vals[j] ? index1[ones_before] : index0[i - ones_before];
            ones_before += vals[j];
        }
    }
    if (e0 + EPT <= n) {
        int4* d4 = reinterpret_cast<int4*>(dst + e0);
        #pragma unroll
        for (int k = 0; k < EPT / 4; ++k)
            d4[k] = make_int4(dv[k*4+0], dv[k*4+1], dv[k*4+2], dv[k*4+3]);
    } else {
        for (int j = 0; j < EPT; ++j) {
            int i = e0 + j;
            if (i < n) dst[i] = dv[j];
        }
    }
}

// ---------- Pass 3: scatter copy — EXACT R6 engine (proven 101.3us) ----------
// Block of 512 threads covers one contiguous 2048-f4 slab (128 rows).
// Sub-slab k: ids [base + k*512, base + k*512 + 512) — fully coalesced NT reads.
// Stores scattered at 256B row granularity (normal/cached).
__global__ __launch_bounds__(512)
void dps_scatter(const f4* __restrict__ data4,
                 const int* __restrict__ dst,
                 f4* __restrict__ out4,
                 long total4) {
    const long base = (long)blockIdx.x * 2048 + threadIdx.x;
    f4   v[4];
    long o[4];
    bool ok[4];
    #pragma unroll
    for (int k = 0; k < 4; ++k) {
        long id = base + (long)k * 512;
        ok[k] = (id < total4);
        if (ok[k]) {
            v[k] = __builtin_nontemporal_load(data4 + id);   // read-once: bypass caches
            int row = (int)(id >> 4);
            int q   = (int)(id & 15);
            o[k] = ((long)dst[row] << 4) + q;                // broadcast across the row's lanes
        }
    }
    #pragma unroll
    for (int k = 0; k < 4; ++k)
        if (ok[k]) out4[o[k]] = v[k];                        // normal (cached) store
}

extern "C" void kernel_launch(void* const* d_in, const int* in_sizes, int n_in,
                              void* d_out, int out_size, void* d_ws, size_t ws_size,
                              hipStream_t stream) {
    const float* data   = (const float*)d_in[0];
    const int*   parts  = (const int*)d_in[1];
    const int*   index0 = (const int*)d_in[2];
    const int*   index1 = (const int*)d_in[3];
    const int n = in_sizes[1];

    int* dst        = (int*)d_ws;              // n ints
    int* block_sums = dst + n;                 // nchunks ints

    const int nchunks = (n + CHUNK - 1) / CHUNK;   // 256 for n = 1<<20

    dps_count<<<nchunks, SCAN_BLOCK, 0, stream>>>(parts, n, block_sums);
    dps_rank <<<nchunks, SCAN_BLOCK, 0, stream>>>(parts, index0, index1, block_sums,
                                                  nchunks, n, dst);

    const long total4 = (long)n << 4;                      // n * (64/4)
    const int  blocks = (int)((total4 + 2047) / 2048);     // 8192 for n = 1<<20
    dps_scatter<<<blocks, 512, 0, stream>>>((const f4*)data, dst, (f4*)d_out, total4);
}